// Round 22
// baseline (272.706 us; speedup 1.0000x reference)
//
#include <hip/hip_runtime.h>
#include <math.h>

#define NMOL 512
#define NATOM 64
#define NFLAT (NMOL*NATOM)
#define AEVL 384
#define FK 448           // fp16 feature row: 384 aev | 32 qraev | q | esp | 30 pad(0)
#define D0 256
#define D1 192
#define D2 160
#define MPAD 33024

typedef _Float16 h8 __attribute__((ext_vector_type(8)));
typedef float    f4 __attribute__((ext_vector_type(4)));

__constant__ float c_sigma[8] = {0.5515909f,1.8886297f,1.3225029f,1.2316629f,
                                 2.1884933f,1.7750372f,1.3677907f,1.3820058f};

__device__ __forceinline__ float wsum(float v){
  #pragma unroll
  for (int o=1;o<64;o<<=1) v += __shfl_xor(v,o);
  return v;
}

// direct global->LDS copy, 16B per lane; lds base must be wave-uniform
__device__ __forceinline__ void gll16(const _Float16* g, _Float16* l){
  __builtin_amdgcn_global_load_lds(
    (const __attribute__((address_space(1))) void*)g,
    (__attribute__((address_space(3))) void*)l, 16, 0, 0);
}

// ======== fused prep (blocks 0..511) + all-layer W transpose (blocks 512..1271) ========
__global__ void prep_wtrans_kernel(const int* __restrict__ species,
                                   const float* __restrict__ coord,
                                   const float* __restrict__ aev,
                                   float* __restrict__ dbuf, float* __restrict__ sig,
                                   float* __restrict__ invj, float* __restrict__ pmf,
                                   int* __restrict__ blkhist, _Float16* __restrict__ feat,
                                   const float* __restrict__ W0c, const float* __restrict__ W1c,
                                   const float* __restrict__ W2c, const float* __restrict__ W0a,
                                   const float* __restrict__ W1a, const float* __restrict__ W2a,
                                   _Float16* __restrict__ T0c, _Float16* __restrict__ T1c,
                                   _Float16* __restrict__ T2c, _Float16* __restrict__ T0a,
                                   _Float16* __restrict__ T1a, _Float16* __restrict__ T2a){
  int b = blockIdx.x, t = threadIdx.x;
  if (b < NMOL){
    int m = b;
    __shared__ float c[192];
    if (t < 192) c[t] = coord[m*192 + t];
    __syncthreads();
    #pragma unroll
    for (int k=0;k<16;k++){
      int p = t + 256*k;
      int i = p >> 6, j = p & 63;
      float dx=c[i*3]-c[j*3], dy=c[i*3+1]-c[j*3+1], dz=c[i*3+2]-c[j*3+2];
      dbuf[m*4096 + p] = sqrtf(dx*dx+dy*dy+dz*dz + 1e-16f) / 0.529177249f;
    }
    if (t < 64){
      int g = m*64+t;
      int s = species[g];
      float sg = c_sigma[s < 0 ? 7 : s];
      sig[g]  = sg;
      invj[g] = 1.7724539f * sg;   // sqrt(pi) fp32
      pmf[g]  = (s>=0) ? 1.f : 0.f;
      #pragma unroll
      for (int sp=0;sp<4;sp++){
        unsigned long long mask = __ballot(s==sp);
        if (t==0) blkhist[m*4+sp] = __popcll(mask);
      }
    }
    // AEV -> fp16 feature rows for this molecule's 64 atoms (tail zeroed)
    const float* aevm = aev + (size_t)m*64*AEVL;
    _Float16* featm = feat + (size_t)m*64*FK;
    for (int j=t; j<64*56; j+=256){
      int al = j/56, cc = j - (j/56)*56;
      int k8 = cc*8;
      h8 o;
      if (k8 < AEVL){
        const f4* sp = reinterpret_cast<const f4*>(aevm + (size_t)al*AEVL + k8);
        f4 a = sp[0], bb = sp[1];
        o[0]=(_Float16)a[0]; o[1]=(_Float16)a[1]; o[2]=(_Float16)a[2]; o[3]=(_Float16)a[3];
        o[4]=(_Float16)bb[0]; o[5]=(_Float16)bb[1]; o[6]=(_Float16)bb[2]; o[7]=(_Float16)bb[3];
      } else {
        #pragma unroll
        for (int e=0;e<8;e++) o[e] = (_Float16)0.f;
      }
      *reinterpret_cast<h8*>(featm + (size_t)al*FK + k8) = o;
    }
  } else {
    // W transpose: [4][K][N] f32 -> [4][KT*4][N][8] fp16, zero-padded
    int bw = b - NMOL;                 // 0..759
    int ublk = bw % 95;
    int s = (bw/95) & 3;
    int ani = bw / 380;
    int u = ublk*256 + t;
    if (u >= 24320) return;
    const float* W; _Float16* T; int K, N, KT;
    if (u < 14336){            W = ani?W0a:W0c; T = ani?T0a:T0c; K=418; N=256; KT=14; }
    else if (u < 20480){ u -= 14336; W = ani?W1a:W1c; T = ani?T1a:T1c; K=256; N=192; KT=8; }
    else               { u -= 20480; W = ani?W2a:W2c; T = ani?T2a:T2c; K=192; N=160; KT=6; }
    int col = u % N;
    int pk  = u / N;            // kt*4+part
    int part = pk & 3, kt = pk >> 2;
    h8 o;
    #pragma unroll
    for (int e=0;e<8;e++){
      int gk = kt*32 + part*8 + e;
      float v = (gk < K) ? W[((size_t)s*K + gk)*N + col] : 0.f;
      o[e] = (_Float16)v;
    }
    *reinterpret_cast<h8*>(T + ((size_t)s*KT*4 + pk)*N*8 + (size_t)col*8) = o;
  }
}

// ======== scatter with in-block plan: each block recomputes the scan locally ========
// meta: [0..3] counts, [4..8] base(64-aligned, [8]=total rows), [9..13] tile_base ([13]=total tiles)
__global__ void scatter_plan_kernel(const int* __restrict__ species,
                                    const int* __restrict__ blkhist,
                                    int* __restrict__ meta,
                                    int* __restrict__ idxarr){
  int m = blockIdx.x, a = threadIdx.x, g = m*64+a;
  __shared__ int h[NMOL*4];
  __shared__ int tot[4], off[4];
  for (int j=a; j<NMOL*4; j+=64) h[j] = blkhist[j];
  __syncthreads();
  if (a < 4){
    int sum = 0, pre = 0;
    for (int j=0;j<NMOL;j++){ int v = h[j*4+a]; if (j < m) pre += v; sum += v; }
    tot[a] = sum; off[a] = pre;
  }
  __syncthreads();
  if (a < 4){
    int base = 0;
    for (int s=0;s<a;s++) base += ((tot[s]+63)>>6)<<6;
    off[a] += base;
  }
  if (m == 0 && a == 0){
    int b=0, tb=0;
    meta[4]=0; meta[9]=0;
    for (int s=0;s<4;s++){
      meta[s] = tot[s];
      int tiles = (tot[s]+63)>>6;
      b  += tiles<<6;  tb += tiles;
      meta[5+s]  = b;  meta[10+s] = tb;
    }
  }
  __syncthreads();
  int s = species[g];
  unsigned long long below = (1ull<<a) - 1ull;
  #pragma unroll
  for (int sp=0;sp<4;sp++){
    unsigned long long mask = __ballot(s==sp);
    if (s==sp){
      int rank = __popcll(mask & below);
      idxarr[off[sp] + rank] = g;
    }
  }
}

// ======== m97-style fp16 MFMA GEMM: A+B staged via global_load_lds, dbuf, 1 barrier/k-step ========
// Block: 64 rows x COLS cols (COLS=NCB*16), 4 waves; wave w: rows [w*16,+16) x all COLS.
// FUSEL3: apply celu and fold the [COLS]-wide W3 dot in-register -> write scalar chi (no C write).
template<int GATHER, int NCB, int KTW, int FUSEL3>
__launch_bounds__(256)
__global__ void gemm_gll(const _Float16* __restrict__ Ah,    // [rows][KTW*32]  (GATHER=0)
                         const _Float16* __restrict__ feat,  // [NFLAT][FK]     (GATHER=1)
                         const int* __restrict__ idxarr,
                         const int* __restrict__ meta,
                         const _Float16* __restrict__ Wt,    // [4][KTW*4][N][8]
                         const float* __restrict__ Ball,     // [4][N]
                         _Float16* __restrict__ C,           // [rows][N] (FUSEL3=0)
                         const float* __restrict__ W3a,      // [4][COLS]  (FUSEL3=1)
                         const float* __restrict__ b3a,      // [4]
                         float* __restrict__ outv,           // [NFLAT]    (FUSEL3=1)
                         int N, int ktrun, int act){
  constexpr int COLS = NCB*16;
  constexpr int NB16 = COLS/16;          // 1KB-instructions per B k-tile
  int t = blockIdx.x;
  if (t >= meta[13]) return;
  int s = 0;
  while (s < 3 && t >= meta[10+s]) s++;
  int trow = t - meta[9+s];
  int row0 = meta[4+s] + (trow<<6);
  int mrem = meta[s] - (trow<<6); if (mrem > 64) mrem = 64;
  int c0 = blockIdx.y * COLS;

  __shared__ __align__(16) _Float16 Ab[2][2048];        // [part][row][8]
  __shared__ __align__(16) _Float16 Bb[2][COLS*32];     // [part][col][8]

  int tid = threadIdx.x;
  int w = tid>>6, l = tid&63, lr16 = l&15, lg = l>>4;

  // per-lane A source row (lane = row within tile)
  int arow = row0 + l;
  int amax = row0 + mrem - 1;
  if (arow > amax) arow = amax;
  const _Float16* asrc;
  if (GATHER) asrc = feat + (size_t)idxarr[arow]*FK;
  else        asrc = Ah + (size_t)arow*(KTW*32);

  const _Float16* Wbase = Wt + (size_t)s*KTW*4*N*8 + (size_t)c0*8;

  // stage k-step kt into buffer buf
  auto STAGE = [&](int buf, int kt){
    gll16(asrc + kt*32 + w*8, &Ab[buf][w*512]);
    for (int j=w; j<NB16; j+=4){
      int u = j*64 + l;
      int part = u / COLS, col = u - part*COLS;
      gll16(Wbase + ((size_t)(kt*4+part)*N + col)*8, &Bb[buf][j*512]);
    }
  };

  f4 acc[NCB];
  #pragma unroll
  for (int c=0;c<NCB;c++){ acc[c][0]=0.f; acc[c][1]=0.f; acc[c][2]=0.f; acc[c][3]=0.f; }

  STAGE(0, 0);
  __syncthreads();
  int cur = 0;
  for (int kt=0; kt<ktrun; ++kt){
    if (kt+1 < ktrun) STAGE(cur^1, kt+1);
    h8 aF = *reinterpret_cast<const h8*>(&Ab[cur][lg*512 + (w*16+lr16)*8]);
    #pragma unroll
    for (int c=0;c<NCB;c++){
      h8 bF = *reinterpret_cast<const h8*>(&Bb[cur][lg*COLS*8 + (c*16+lr16)*8]);
      acc[c] = __builtin_amdgcn_mfma_f32_16x16x32_f16(aF, bF, acc[c], 0, 0, 0);
    }
    if (kt+1 < ktrun){
      __syncthreads();
      cur ^= 1;
    }
  }

  // epilogue: C/D layout col=lane&15, row=(lane>>4)*4+reg (HW-verified)
  const float* bias = Ball + s*N;
  if (FUSEL3){
    // celu + W3 dot entirely in-register; 16-lane (lr16) reduce covers all COLS cols
    const float* w3 = W3a + s*COLS;
    float vrow[4] = {0.f,0.f,0.f,0.f};
    #pragma unroll
    for (int c=0;c<NCB;c++){
      int col = c*16 + lr16;
      float bsv = bias[col];
      float wv  = w3[col];
      #pragma unroll
      for (int rr=0;rr<4;rr++){
        float vv = acc[c][rr] + bsv;
        vv = vv > 0.f ? vv : 0.1f*expm1f(vv*10.f);
        vrow[rr] += vv * wv;
      }
    }
    float b3v = b3a[s];
    #pragma unroll
    for (int rr=0;rr<4;rr++){
      float v = vrow[rr];
      #pragma unroll
      for (int o=1;o<16;o<<=1) v += __shfl_xor(v, o);
      int lrow = w*16 + lg*4 + rr;
      if (lr16 == 0 && lrow < mrem)
        outv[idxarr[row0+lrow]] = v + b3v;
    }
  } else {
    #pragma unroll
    for (int c=0;c<NCB;c++){
      int col = c0 + c*16 + lr16;
      float bsv = bias[col];
      #pragma unroll
      for (int rr=0;rr<4;rr++){
        int lrow = w*16 + lg*4 + rr;
        if (lrow >= mrem) continue;
        float vv = acc[c][rr] + bsv;
        if (act) vv = vv > 0.f ? vv : 0.1f*expm1f(vv*10.f);
        C[(size_t)(row0+lrow)*N + col] = (_Float16)vv;
      }
    }
  }
}

// ---- fused charge iteration (512 thr): qupdate + esp(symmetric f-matrix) + qraev ----
__global__ void iter_kernel(const float* __restrict__ chi, const float* __restrict__ invj,
                            const float* __restrict__ pmf, const float* __restrict__ netq,
                            const float* __restrict__ dbuf, const float* __restrict__ sig,
                            float* __restrict__ q, _Float16* __restrict__ feat){
  int m = blockIdx.x, tid = threadIdx.x;
  int i = tid & 63, w = tid >> 6;   // w in 0..7
  __shared__ float qs[64], pms[64], sg2[64];
  __shared__ float esp8[8][64];
  __shared__ float qr[8][64][8];
  __shared__ float fm[64][65];      // symmetric erf/d matrix (pad 65: conflict-free)
  if (tid < 64){
    int g = m*64 + i;
    float pm = pmf[g], ij = invj[g];
    float c = pm > 0.f ? chi[g] : 0.f;
    float num = wsum(c*ij);
    float den = wsum(ij*pm);
    float corr = (netq[m] + num) / den;
    float qa = -ij*(c - corr)*pm;
    q[g] = qa;
    feat[(size_t)g*FK + 416] = (_Float16)qa;
    qs[i] = qa; pms[i] = pm;
    float s0 = sig[g]; sg2[i] = s0*s0;
  }
  __syncthreads();
  const float* dr = dbuf + (size_t)m*4096;
  // esp phase A: each unordered pair's erf computed once (j > i), mirrored into fm
  {
    float si2 = sg2[i];
    #pragma unroll
    for (int jj=0;jj<8;jj++){
      int j = w*8 + jj;
      if (j > i){
        float d = dr[j*64 + i];
        float ss = fmaxf(si2 + sg2[j], 1e-8f);
        float fv = erff(d/sqrtf(2.f*ss))/d;
        fm[i][j] = fv;
        fm[j][i] = fv;
      }
    }
  }
  // qraev (exp recurrence): wave w = (jh<<2)|bg
  {
    const float STEP = 0.264516129f;     // 8.2/31
    const float C2 = 0.7558781f;         // exp(-4*STEP^2)
    const float C1 = 0.5713518f;         // exp(-8*STEP^2)
    int jh = w>>2, bg = w&3;
    float rbase = 0.8f + (bg*8)*STEP;
    float pmi = pms[i];
    float acc[8] = {0.f,0.f,0.f,0.f,0.f,0.f,0.f,0.f};
    for (int jj=0;jj<32;jj++){
      int j = jh*32 + jj;
      if (j==i) continue;
      float d = dr[j*64+i];
      if (d < 10.f){
        float wq = 0.25f*(0.5f*__cosf(0.31415927f*d)+0.5f)*qs[j]*pms[j]*pmi;
        if (wq != 0.f){
          float t0 = d - rbase;
          float fv = __expf(-4.f*t0*t0);
          float gv = __expf(2.116129f*t0)*C2;
          #pragma unroll
          for (int r=0;r<8;r++){ acc[r] += wq*fv; fv *= gv; gv *= C1; }
        }
      }
    }
    #pragma unroll
    for (int r=0;r<8;r++) qr[w][i][r] = acc[r];
  }
  __syncthreads();
  // esp phase B: transcendental-free row-sum (same values, same order -> bit-identical)
  {
    float acc = 0.f;
    #pragma unroll
    for (int jj=0;jj<8;jj++){
      int j = w*8 + jj;
      if (j != i) acc += qs[j]*pms[j]*fm[i][j];
    }
    esp8[w][i] = acc;
  }
  __syncthreads();
  if (tid < 64){
    int g = m*64+i;
    float e = 0.f;
    #pragma unroll
    for (int k=0;k<8;k++) e += esp8[k][i];
    feat[(size_t)g*FK + 417] = (_Float16)(e * pms[i]);
  }
  if (tid < 256){
    int ii = tid & 63, bg = tid >> 6;
    h8 o;
    #pragma unroll
    for (int r=0;r<8;r++) o[r] = (_Float16)(qr[bg][ii][r] + qr[bg+4][ii][r]);
    *reinterpret_cast<h8*>(feat + (size_t)(m*64+ii)*FK + 384 + bg*8) = o;
  }
}

// ---------------- screened Coulomb + energy + outputs (256 thr, 4-way split) ----------------
__global__ void final_kernel(const float* __restrict__ dbuf, const float* __restrict__ q,
                             const float* __restrict__ pmf, const float* __restrict__ ae,
                             const int* __restrict__ species, float* __restrict__ out){
  int m = blockIdx.x, tid = threadIdx.x;
  int a = tid & 63, w = tid >> 6;
  int g = m*64 + a;
  __shared__ float qs[64], pms[64], c4[4][64];
  if (tid < 64){ qs[a]=q[g]; pms[a]=pmf[g]; }
  __syncthreads();
  float acc=0.f;
  const float* dr = dbuf + (size_t)m*4096;
  #pragma unroll
  for (int jj=0;jj<16;jj++){
    int b = w*16 + jj;
    if (b==a) continue;
    float d = dr[b*64+a];
    float sgm = 1.f/(1.f+__expf(-(d-2.2f)*8.5f));
    acc += qs[b]*pms[b]*sgm/d;
  }
  c4[w][a] = acc;
  __syncthreads();
  if (tid < 64){
    float at = c4[0][a]+c4[1][a]+c4[2][a]+c4[3][a];
    float e = 0.5f*qs[a]*pms[a]*at;          // triu(k=1) sum of symmetric matrix
    float aea = pms[a]>0.f ? ae[g] : 0.f;
    float tot = wsum(e + aea);
    if (a == 0) out[NFLAT + m] = tot;
    out[g] = (float)species[g];
    out[NFLAT + NMOL + g] = qs[a];
  }
}

extern "C" void kernel_launch(void* const* d_in, const int* in_sizes, int n_in,
                              void* d_out, int out_size, void* d_ws, size_t ws_size,
                              hipStream_t stream){
  const int*   species = (const int*)d_in[0];
  const float* coord   = (const float*)d_in[1];
  const float* netq    = (const float*)d_in[2];
  const float* aev     = (const float*)d_in[3];
  const float* cW[4] = {(const float*)d_in[4],(const float*)d_in[6],(const float*)d_in[8],(const float*)d_in[10]};
  const float* cB[4] = {(const float*)d_in[5],(const float*)d_in[7],(const float*)d_in[9],(const float*)d_in[11]};
  const float* aW[4] = {(const float*)d_in[12],(const float*)d_in[14],(const float*)d_in[16],(const float*)d_in[18]};
  const float* aB[4] = {(const float*)d_in[13],(const float*)d_in[15],(const float*)d_in[17],(const float*)d_in[19]};

  // workspace layout (float units; fp16 regions counted as elems/2, all 16B-aligned)
  float* f = (float*)d_ws;
  size_t o = 0;
  float* dbuf  = f + o; o += (size_t)NMOL*4096;
  float* sig   = f + o; o += NFLAT;
  float* invj  = f + o; o += NFLAT;
  float* pmf   = f + o; o += NFLAT;
  float* q     = f + o; o += NFLAT;
  float* chi   = f + o; o += NFLAT;
  _Float16* feat = (_Float16*)(f + o); o += (size_t)NFLAT*FK/2;
  _Float16* h0h  = (_Float16*)(f + o); o += (size_t)MPAD*D0/2;
  _Float16* h1h  = (_Float16*)(f + o); o += (size_t)MPAD*D1/2;
  // Wt[i]: [4][KT*4][N][8] fp16
  const int KT_[3] = {14, 8, 6};
  const int N_[3]  = {D0, D1, D2};
  _Float16* wt[6];
  for (int i=0;i<6;i++){
    wt[i] = (_Float16*)(f + o);
    o += (size_t)4*KT_[i%3]*N_[i%3]*32/2;
  }
  int* meta    = (int*)(f + o); o += 64;
  int* idxarr  = (int*)(f + o); o += MPAD;
  int* blkhist = (int*)(f + o); o += NMOL*4;

  // ---- one-time prep: fused prep + W transpose, then fused plan+scatter ----
  prep_wtrans_kernel<<<dim3(NMOL + 760), 256, 0, stream>>>(
      species, coord, aev, dbuf, sig, invj, pmf, blkhist, feat,
      cW[0], cW[1], cW[2], aW[0], aW[1], aW[2],
      wt[0], wt[1], wt[2], wt[3], wt[4], wt[5]);
  scatter_plan_kernel<<<dim3(NMOL), 64, 0, stream>>>(species, blkhist, meta, idxarr);

  for (int pass=0; pass<3; ++pass){
    int wb = (pass<2) ? 0 : 3;
    const float* const* Bp = (pass<2) ? cB : aB;
    const float* W3 = (pass<2) ? cW[3] : aW[3];
    const float* b3 = (pass<2) ? cB[3] : aB[3];
    int kt0 = (pass==0) ? 12 : 14;   // pass-0: extra features exactly zero -> skip 2 k-steps
    gemm_gll<1,4,14,0><<<dim3(516,4), 256, 0, stream>>>(nullptr, feat, idxarr, meta,
                                                        wt[wb+0], Bp[0], h0h,
                                                        nullptr, nullptr, nullptr, D0, kt0, 1);
    gemm_gll<0,3,8,0><<<dim3(516,4), 256, 0, stream>>>(h0h, nullptr, idxarr, meta,
                                                       wt[wb+1], Bp[1], h1h,
                                                       nullptr, nullptr, nullptr, D1, 8, 1);
    gemm_gll<0,10,6,1><<<dim3(516,1), 256, 0, stream>>>(h1h, nullptr, idxarr, meta,
                                                        wt[wb+2], Bp[2], nullptr,
                                                        W3, b3, chi, D2, 6, 1);
    if (pass < 2)
      iter_kernel<<<dim3(NMOL), 512, 0, stream>>>(chi, invj, pmf, netq, dbuf, sig, q, feat);
  }
  final_kernel<<<dim3(NMOL), 256, 0, stream>>>(dbuf, q, pmf, chi, species, (float*)d_out);
}

// Round 23
// 253.181 us; speedup vs baseline: 1.0771x; 1.0771x over previous
//
#include <hip/hip_runtime.h>
#include <math.h>

#define NMOL 512
#define NATOM 64
#define NFLAT (NMOL*NATOM)
#define AEVL 384
#define FK 448           // fp16 feature row: 384 aev | 32 qraev | q | esp | 30 pad(0)
#define D0 256
#define D1 192
#define D2 160
#define MPAD 33024

typedef _Float16 h8 __attribute__((ext_vector_type(8)));
typedef float    f4 __attribute__((ext_vector_type(4)));

__constant__ float c_sigma[8] = {0.5515909f,1.8886297f,1.3225029f,1.2316629f,
                                 2.1884933f,1.7750372f,1.3677907f,1.3820058f};

__device__ __forceinline__ float wsum(float v){
  #pragma unroll
  for (int o=1;o<64;o<<=1) v += __shfl_xor(v,o);
  return v;
}

// direct global->LDS copy, 16B per lane; lds base must be wave-uniform
__device__ __forceinline__ void gll16(const _Float16* g, _Float16* l){
  __builtin_amdgcn_global_load_lds(
    (const __attribute__((address_space(1))) void*)g,
    (__attribute__((address_space(3))) void*)l, 16, 0, 0);
}

// ======== fused prep (blocks 0..511) + all-layer W transpose (blocks 512..1271) ========
__global__ void prep_wtrans_kernel(const int* __restrict__ species,
                                   const float* __restrict__ coord,
                                   const float* __restrict__ aev,
                                   float* __restrict__ dbuf, float* __restrict__ sig,
                                   float* __restrict__ invj, float* __restrict__ pmf,
                                   int* __restrict__ blkhist, _Float16* __restrict__ feat,
                                   const float* __restrict__ W0c, const float* __restrict__ W1c,
                                   const float* __restrict__ W2c, const float* __restrict__ W0a,
                                   const float* __restrict__ W1a, const float* __restrict__ W2a,
                                   _Float16* __restrict__ T0c, _Float16* __restrict__ T1c,
                                   _Float16* __restrict__ T2c, _Float16* __restrict__ T0a,
                                   _Float16* __restrict__ T1a, _Float16* __restrict__ T2a){
  int b = blockIdx.x, t = threadIdx.x;
  if (b < NMOL){
    int m = b;
    __shared__ float c[192];
    if (t < 192) c[t] = coord[m*192 + t];
    __syncthreads();
    #pragma unroll
    for (int k=0;k<16;k++){
      int p = t + 256*k;
      int i = p >> 6, j = p & 63;
      float dx=c[i*3]-c[j*3], dy=c[i*3+1]-c[j*3+1], dz=c[i*3+2]-c[j*3+2];
      dbuf[m*4096 + p] = sqrtf(dx*dx+dy*dy+dz*dz + 1e-16f) / 0.529177249f;
    }
    if (t < 64){
      int g = m*64+t;
      int s = species[g];
      float sg = c_sigma[s < 0 ? 7 : s];
      sig[g]  = sg;
      invj[g] = 1.7724539f * sg;   // sqrt(pi) fp32
      pmf[g]  = (s>=0) ? 1.f : 0.f;
      #pragma unroll
      for (int sp=0;sp<4;sp++){
        unsigned long long mask = __ballot(s==sp);
        if (t==0) blkhist[m*4+sp] = __popcll(mask);
      }
    }
    // AEV -> fp16 feature rows for this molecule's 64 atoms (tail zeroed)
    const float* aevm = aev + (size_t)m*64*AEVL;
    _Float16* featm = feat + (size_t)m*64*FK;
    for (int j=t; j<64*56; j+=256){
      int al = j/56, cc = j - (j/56)*56;
      int k8 = cc*8;
      h8 o;
      if (k8 < AEVL){
        const f4* sp = reinterpret_cast<const f4*>(aevm + (size_t)al*AEVL + k8);
        f4 a = sp[0], bb = sp[1];
        o[0]=(_Float16)a[0]; o[1]=(_Float16)a[1]; o[2]=(_Float16)a[2]; o[3]=(_Float16)a[3];
        o[4]=(_Float16)bb[0]; o[5]=(_Float16)bb[1]; o[6]=(_Float16)bb[2]; o[7]=(_Float16)bb[3];
      } else {
        #pragma unroll
        for (int e=0;e<8;e++) o[e] = (_Float16)0.f;
      }
      *reinterpret_cast<h8*>(featm + (size_t)al*FK + k8) = o;
    }
  } else {
    // W transpose: [4][K][N] f32 -> [4][KT*4][N][8] fp16, zero-padded
    int bw = b - NMOL;                 // 0..759
    int ublk = bw % 95;
    int s = (bw/95) & 3;
    int ani = bw / 380;
    int u = ublk*256 + t;
    if (u >= 24320) return;
    const float* W; _Float16* T; int K, N, KT;
    if (u < 14336){            W = ani?W0a:W0c; T = ani?T0a:T0c; K=418; N=256; KT=14; }
    else if (u < 20480){ u -= 14336; W = ani?W1a:W1c; T = ani?T1a:T1c; K=256; N=192; KT=8; }
    else               { u -= 20480; W = ani?W2a:W2c; T = ani?T2a:T2c; K=192; N=160; KT=6; }
    int col = u % N;
    int pk  = u / N;            // kt*4+part
    int part = pk & 3, kt = pk >> 2;
    h8 o;
    #pragma unroll
    for (int e=0;e<8;e++){
      int gk = kt*32 + part*8 + e;
      float v = (gk < K) ? W[((size_t)s*K + gk)*N + col] : 0.f;
      o[e] = (_Float16)v;
    }
    *reinterpret_cast<h8*>(T + ((size_t)s*KT*4 + pk)*N*8 + (size_t)col*8) = o;
  }
}

// ======== scatter with in-block plan: each block recomputes the scan locally ========
// meta: [0..3] counts, [4..8] base(64-aligned, [8]=total rows), [9..13] tile_base ([13]=total tiles)
__global__ void scatter_plan_kernel(const int* __restrict__ species,
                                    const int* __restrict__ blkhist,
                                    int* __restrict__ meta,
                                    int* __restrict__ idxarr){
  int m = blockIdx.x, a = threadIdx.x, g = m*64+a;
  __shared__ int h[NMOL*4];
  __shared__ int tot[4], off[4];
  for (int j=a; j<NMOL*4; j+=64) h[j] = blkhist[j];
  __syncthreads();
  if (a < 4){
    int sum = 0, pre = 0;
    for (int j=0;j<NMOL;j++){ int v = h[j*4+a]; if (j < m) pre += v; sum += v; }
    tot[a] = sum; off[a] = pre;
  }
  __syncthreads();
  if (a < 4){
    int base = 0;
    for (int s=0;s<a;s++) base += ((tot[s]+63)>>6)<<6;
    off[a] += base;
  }
  if (m == 0 && a == 0){
    int b=0, tb=0;
    meta[4]=0; meta[9]=0;
    for (int s=0;s<4;s++){
      meta[s] = tot[s];
      int tiles = (tot[s]+63)>>6;
      b  += tiles<<6;  tb += tiles;
      meta[5+s]  = b;  meta[10+s] = tb;
    }
  }
  __syncthreads();
  int s = species[g];
  unsigned long long below = (1ull<<a) - 1ull;
  #pragma unroll
  for (int sp=0;sp<4;sp++){
    unsigned long long mask = __ballot(s==sp);
    if (s==sp){
      int rank = __popcll(mask & below);
      idxarr[off[sp] + rank] = g;
    }
  }
}

// ======== m97-style fp16 MFMA GEMM: A+B staged via global_load_lds, dbuf, 1 barrier/k-step ========
// Block: 64 rows x COLS cols (COLS=NCB*16), 4 waves; wave w: rows [w*16,+16) x all COLS.
// FUSEL3: apply celu and fold the [COLS]-wide W3 dot in-register -> write scalar chi (no C write).
template<int GATHER, int NCB, int KTW, int FUSEL3>
__launch_bounds__(256)
__global__ void gemm_gll(const _Float16* __restrict__ Ah,    // [rows][KTW*32]  (GATHER=0)
                         const _Float16* __restrict__ feat,  // [NFLAT][FK]     (GATHER=1)
                         const int* __restrict__ idxarr,
                         const int* __restrict__ meta,
                         const _Float16* __restrict__ Wt,    // [4][KTW*4][N][8]
                         const float* __restrict__ Ball,     // [4][N]
                         _Float16* __restrict__ C,           // [rows][N] (FUSEL3=0)
                         const float* __restrict__ W3a,      // [4][COLS]  (FUSEL3=1)
                         const float* __restrict__ b3a,      // [4]
                         float* __restrict__ outv,           // [NFLAT]    (FUSEL3=1)
                         int N, int ktrun, int act){
  constexpr int COLS = NCB*16;
  constexpr int NB16 = COLS/16;          // 1KB-instructions per B k-tile
  int t = blockIdx.x;
  if (t >= meta[13]) return;
  int s = 0;
  while (s < 3 && t >= meta[10+s]) s++;
  int trow = t - meta[9+s];
  int row0 = meta[4+s] + (trow<<6);
  int mrem = meta[s] - (trow<<6); if (mrem > 64) mrem = 64;
  int c0 = blockIdx.y * COLS;

  __shared__ __align__(16) _Float16 Ab[2][2048];        // [part][row][8]
  __shared__ __align__(16) _Float16 Bb[2][COLS*32];     // [part][col][8]

  int tid = threadIdx.x;
  int w = tid>>6, l = tid&63, lr16 = l&15, lg = l>>4;

  // per-lane A source row (lane = row within tile)
  int arow = row0 + l;
  int amax = row0 + mrem - 1;
  if (arow > amax) arow = amax;
  const _Float16* asrc;
  if (GATHER) asrc = feat + (size_t)idxarr[arow]*FK;
  else        asrc = Ah + (size_t)arow*(KTW*32);

  const _Float16* Wbase = Wt + (size_t)s*KTW*4*N*8 + (size_t)c0*8;

  // stage k-step kt into buffer buf
  auto STAGE = [&](int buf, int kt){
    gll16(asrc + kt*32 + w*8, &Ab[buf][w*512]);
    for (int j=w; j<NB16; j+=4){
      int u = j*64 + l;
      int part = u / COLS, col = u - part*COLS;
      gll16(Wbase + ((size_t)(kt*4+part)*N + col)*8, &Bb[buf][j*512]);
    }
  };

  f4 acc[NCB];
  #pragma unroll
  for (int c=0;c<NCB;c++){ acc[c][0]=0.f; acc[c][1]=0.f; acc[c][2]=0.f; acc[c][3]=0.f; }

  STAGE(0, 0);
  __syncthreads();
  int cur = 0;
  for (int kt=0; kt<ktrun; ++kt){
    if (kt+1 < ktrun) STAGE(cur^1, kt+1);
    h8 aF = *reinterpret_cast<const h8*>(&Ab[cur][lg*512 + (w*16+lr16)*8]);
    #pragma unroll
    for (int c=0;c<NCB;c++){
      h8 bF = *reinterpret_cast<const h8*>(&Bb[cur][lg*COLS*8 + (c*16+lr16)*8]);
      acc[c] = __builtin_amdgcn_mfma_f32_16x16x32_f16(aF, bF, acc[c], 0, 0, 0);
    }
    if (kt+1 < ktrun){
      __syncthreads();
      cur ^= 1;
    }
  }

  // epilogue: C/D layout col=lane&15, row=(lane>>4)*4+reg (HW-verified)
  const float* bias = Ball + s*N;
  if (FUSEL3){
    // celu + W3 dot entirely in-register; 16-lane (lr16) reduce covers all COLS cols
    const float* w3 = W3a + s*COLS;
    float vrow[4] = {0.f,0.f,0.f,0.f};
    #pragma unroll
    for (int c=0;c<NCB;c++){
      int col = c*16 + lr16;
      float bsv = bias[col];
      float wv  = w3[col];
      #pragma unroll
      for (int rr=0;rr<4;rr++){
        float vv = acc[c][rr] + bsv;
        vv = vv > 0.f ? vv : 0.1f*expm1f(vv*10.f);
        vrow[rr] += vv * wv;
      }
    }
    float b3v = b3a[s];
    #pragma unroll
    for (int rr=0;rr<4;rr++){
      float v = vrow[rr];
      #pragma unroll
      for (int o=1;o<16;o<<=1) v += __shfl_xor(v, o);
      int lrow = w*16 + lg*4 + rr;
      if (lr16 == 0 && lrow < mrem)
        outv[idxarr[row0+lrow]] = v + b3v;
    }
  } else {
    #pragma unroll
    for (int c=0;c<NCB;c++){
      int col = c0 + c*16 + lr16;
      float bsv = bias[col];
      #pragma unroll
      for (int rr=0;rr<4;rr++){
        int lrow = w*16 + lg*4 + rr;
        if (lrow >= mrem) continue;
        float vv = acc[c][rr] + bsv;
        if (act) vv = vv > 0.f ? vv : 0.1f*expm1f(vv*10.f);
        C[(size_t)(row0+lrow)*N + col] = (_Float16)vv;
      }
    }
  }
}

// ---- fused charge iteration (512 thr): qupdate + esp(symmetric f-matrix) + qraev ----
__global__ void iter_kernel(const float* __restrict__ chi, const float* __restrict__ invj,
                            const float* __restrict__ pmf, const float* __restrict__ netq,
                            const float* __restrict__ dbuf, const float* __restrict__ sig,
                            float* __restrict__ q, _Float16* __restrict__ feat){
  int m = blockIdx.x, tid = threadIdx.x;
  int i = tid & 63, w = tid >> 6;   // w in 0..7
  __shared__ float qs[64], pms[64], sg2[64];
  __shared__ float esp8[8][64];
  __shared__ float qr[8][64][8];
  __shared__ float fm[64][65];      // symmetric erf/d matrix (pad 65: conflict-free)
  if (tid < 64){
    int g = m*64 + i;
    float pm = pmf[g], ij = invj[g];
    float c = pm > 0.f ? chi[g] : 0.f;
    float num = wsum(c*ij);
    float den = wsum(ij*pm);
    float corr = (netq[m] + num) / den;
    float qa = -ij*(c - corr)*pm;
    q[g] = qa;
    feat[(size_t)g*FK + 416] = (_Float16)qa;
    qs[i] = qa; pms[i] = pm;
    float s0 = sig[g]; sg2[i] = s0*s0;
  }
  __syncthreads();
  const float* dr = dbuf + (size_t)m*4096;
  // esp phase A: each unordered pair's erf computed once (j > i), mirrored into fm
  {
    float si2 = sg2[i];
    #pragma unroll
    for (int jj=0;jj<8;jj++){
      int j = w*8 + jj;
      if (j > i){
        float d = dr[j*64 + i];
        float ss = fmaxf(si2 + sg2[j], 1e-8f);
        float fv = erff(d/sqrtf(2.f*ss))/d;
        fm[i][j] = fv;
        fm[j][i] = fv;
      }
    }
  }
  // qraev (exp recurrence): wave w = (jh<<2)|bg
  {
    const float STEP = 0.264516129f;     // 8.2/31
    const float C2 = 0.7558781f;         // exp(-4*STEP^2)
    const float C1 = 0.5713518f;         // exp(-8*STEP^2)
    int jh = w>>2, bg = w&3;
    float rbase = 0.8f + (bg*8)*STEP;
    float pmi = pms[i];
    float acc[8] = {0.f,0.f,0.f,0.f,0.f,0.f,0.f,0.f};
    for (int jj=0;jj<32;jj++){
      int j = jh*32 + jj;
      if (j==i) continue;
      float d = dr[j*64+i];
      if (d < 10.f){
        float wq = 0.25f*(0.5f*__cosf(0.31415927f*d)+0.5f)*qs[j]*pms[j]*pmi;
        if (wq != 0.f){
          float t0 = d - rbase;
          float fv = __expf(-4.f*t0*t0);
          float gv = __expf(2.116129f*t0)*C2;
          #pragma unroll
          for (int r=0;r<8;r++){ acc[r] += wq*fv; fv *= gv; gv *= C1; }
        }
      }
    }
    #pragma unroll
    for (int r=0;r<8;r++) qr[w][i][r] = acc[r];
  }
  __syncthreads();
  // esp phase B: transcendental-free row-sum (same values, same order -> bit-identical)
  {
    float acc = 0.f;
    #pragma unroll
    for (int jj=0;jj<8;jj++){
      int j = w*8 + jj;
      if (j != i) acc += qs[j]*pms[j]*fm[i][j];
    }
    esp8[w][i] = acc;
  }
  __syncthreads();
  if (tid < 64){
    int g = m*64+i;
    float e = 0.f;
    #pragma unroll
    for (int k=0;k<8;k++) e += esp8[k][i];
    feat[(size_t)g*FK + 417] = (_Float16)(e * pms[i]);
  }
  if (tid < 256){
    int ii = tid & 63, bg = tid >> 6;
    h8 o;
    #pragma unroll
    for (int r=0;r<8;r++) o[r] = (_Float16)(qr[bg][ii][r] + qr[bg+4][ii][r]);
    *reinterpret_cast<h8*>(feat + (size_t)(m*64+ii)*FK + 384 + bg*8) = o;
  }
}

// ---------------- screened Coulomb + energy + outputs (256 thr, 4-way split) ----------------
__global__ void final_kernel(const float* __restrict__ dbuf, const float* __restrict__ q,
                             const float* __restrict__ pmf, const float* __restrict__ ae,
                             const int* __restrict__ species, float* __restrict__ out){
  int m = blockIdx.x, tid = threadIdx.x;
  int a = tid & 63, w = tid >> 6;
  int g = m*64 + a;
  __shared__ float qs[64], pms[64], c4[4][64];
  if (tid < 64){ qs[a]=q[g]; pms[a]=pmf[g]; }
  __syncthreads();
  float acc=0.f;
  const float* dr = dbuf + (size_t)m*4096;
  #pragma unroll
  for (int jj=0;jj<16;jj++){
    int b = w*16 + jj;
    if (b==a) continue;
    float d = dr[b*64+a];
    float sgm = 1.f/(1.f+__expf(-(d-2.2f)*8.5f));
    acc += qs[b]*pms[b]*sgm/d;
  }
  c4[w][a] = acc;
  __syncthreads();
  if (tid < 64){
    float at = c4[0][a]+c4[1][a]+c4[2][a]+c4[3][a];
    float e = 0.5f*qs[a]*pms[a]*at;          // triu(k=1) sum of symmetric matrix
    float aea = pms[a]>0.f ? ae[g] : 0.f;
    float tot = wsum(e + aea);
    if (a == 0) out[NFLAT + m] = tot;
    out[g] = (float)species[g];
    out[NFLAT + NMOL + g] = qs[a];
  }
}

extern "C" void kernel_launch(void* const* d_in, const int* in_sizes, int n_in,
                              void* d_out, int out_size, void* d_ws, size_t ws_size,
                              hipStream_t stream){
  const int*   species = (const int*)d_in[0];
  const float* coord   = (const float*)d_in[1];
  const float* netq    = (const float*)d_in[2];
  const float* aev     = (const float*)d_in[3];
  const float* cW[4] = {(const float*)d_in[4],(const float*)d_in[6],(const float*)d_in[8],(const float*)d_in[10]};
  const float* cB[4] = {(const float*)d_in[5],(const float*)d_in[7],(const float*)d_in[9],(const float*)d_in[11]};
  const float* aW[4] = {(const float*)d_in[12],(const float*)d_in[14],(const float*)d_in[16],(const float*)d_in[18]};
  const float* aB[4] = {(const float*)d_in[13],(const float*)d_in[15],(const float*)d_in[17],(const float*)d_in[19]};

  // workspace layout (float units; fp16 regions counted as elems/2, all 16B-aligned)
  float* f = (float*)d_ws;
  size_t o = 0;
  float* dbuf  = f + o; o += (size_t)NMOL*4096;
  float* sig   = f + o; o += NFLAT;
  float* invj  = f + o; o += NFLAT;
  float* pmf   = f + o; o += NFLAT;
  float* q     = f + o; o += NFLAT;
  float* chi   = f + o; o += NFLAT;
  _Float16* feat = (_Float16*)(f + o); o += (size_t)NFLAT*FK/2;
  _Float16* h0h  = (_Float16*)(f + o); o += (size_t)MPAD*D0/2;
  _Float16* h1h  = (_Float16*)(f + o); o += (size_t)MPAD*D1/2;
  // Wt[i]: [4][KT*4][N][8] fp16
  const int KT_[3] = {14, 8, 6};
  const int N_[3]  = {D0, D1, D2};
  _Float16* wt[6];
  for (int i=0;i<6;i++){
    wt[i] = (_Float16*)(f + o);
    o += (size_t)4*KT_[i%3]*N_[i%3]*32/2;
  }
  int* meta    = (int*)(f + o); o += 64;
  int* idxarr  = (int*)(f + o); o += MPAD;
  int* blkhist = (int*)(f + o); o += NMOL*4;

  // ---- one-time prep: fused prep + W transpose, then fused plan+scatter ----
  prep_wtrans_kernel<<<dim3(NMOL + 760), 256, 0, stream>>>(
      species, coord, aev, dbuf, sig, invj, pmf, blkhist, feat,
      cW[0], cW[1], cW[2], aW[0], aW[1], aW[2],
      wt[0], wt[1], wt[2], wt[3], wt[4], wt[5]);
  scatter_plan_kernel<<<dim3(NMOL), 64, 0, stream>>>(species, blkhist, meta, idxarr);

  for (int pass=0; pass<3; ++pass){
    int wb = (pass<2) ? 0 : 3;
    const float* const* Bp = (pass<2) ? cB : aB;
    const float* W3 = (pass<2) ? cW[3] : aW[3];
    const float* b3 = (pass<2) ? cB[3] : aB[3];
    int kt0 = (pass==0) ? 12 : 14;   // pass-0: extra features exactly zero -> skip 2 k-steps
    gemm_gll<1,8,14,0><<<dim3(516,2), 256, 0, stream>>>(nullptr, feat, idxarr, meta,
                                                        wt[wb+0], Bp[0], h0h,
                                                        nullptr, nullptr, nullptr, D0, kt0, 1);
    gemm_gll<0,6,8,0><<<dim3(516,2), 256, 0, stream>>>(h0h, nullptr, idxarr, meta,
                                                       wt[wb+1], Bp[1], h1h,
                                                       nullptr, nullptr, nullptr, D1, 8, 1);
    gemm_gll<0,10,6,1><<<dim3(516,1), 256, 0, stream>>>(h1h, nullptr, idxarr, meta,
                                                        wt[wb+2], Bp[2], nullptr,
                                                        W3, b3, chi, D2, 6, 1);
    if (pass < 2)
      iter_kernel<<<dim3(NMOL), 512, 0, stream>>>(chi, invj, pmf, netq, dbuf, sig, q, feat);
  }
  final_kernel<<<dim3(NMOL), 256, 0, stream>>>(dbuf, q, pmf, chi, species, (float*)d_out);
}